// Round 3
// baseline (1100.125 us; speedup 1.0000x reference)
//
#include <hip/hip_runtime.h>
#include <hip/hip_bf16.h>
#include <cstddef>

#define B 64
#define S 128
#define H 1024
#define V 32000
#define T 10
#define H3 3072

typedef __bf16 bf16x8 __attribute__((ext_vector_type(8)));
typedef float f32x4 __attribute__((ext_vector_type(4)));
typedef unsigned short ushort8v __attribute__((ext_vector_type(8)));

__device__ inline unsigned short f2b(float f) {
    __hip_bfloat16 h = __float2bfloat16(f);
    return *reinterpret_cast<unsigned short*>(&h);
}
__device__ inline float b2f(unsigned short u) {
    return __uint_as_float(((unsigned)u) << 16);
}

// ---------------- one-time conversion / build kernels ----------------

__global__ void conv_f2b(const float* __restrict__ src, unsigned short* __restrict__ dst, int n4) {
    int i = blockIdx.x * 256 + threadIdx.x;
    if (i >= n4) return;
    float4 v = reinterpret_cast<const float4*>(src)[i];
    ushort4 o = { f2b(v.x), f2b(v.y), f2b(v.z), f2b(v.w) };
    reinterpret_cast<ushort4*>(dst)[i] = o;
}

// Wcat[4096,1024] = rows 0..3071: gru_wh ; rows 3072..4095: Wa_w (bf16)
__global__ void build_wcat(const float* __restrict__ gwh, const float* __restrict__ Wa_w,
                           unsigned short* __restrict__ dst) {
    int i = blockIdx.x * 256 + threadIdx.x;
    int e = i * 4;
    int n = e >> 10, k = e & 1023;
    const float* src = (n < H3) ? (gwh + (size_t)n * H + k) : (Wa_w + (size_t)(n - H3) * H + k);
    float4 v = *reinterpret_cast<const float4*>(src);
    ushort4 o = { f2b(v.x), f2b(v.y), f2b(v.z), f2b(v.w) };
    reinterpret_cast<ushort4*>(dst)[i] = o;
}

__global__ void build_catbias(const float* __restrict__ gbh, const float* __restrict__ Wa_b,
                              float* __restrict__ dst) {
    int n = blockIdx.x * 256 + threadIdx.x;
    dst[n] = (n < H3) ? gbh[n] : Wa_b[n - H3];
}

__global__ void build_wslice(const float* __restrict__ gwi, unsigned short* __restrict__ dst, int off) {
    int i = blockIdx.x * 256 + threadIdx.x;
    int e = i * 4;
    int n = e >> 10, k = e & 1023;
    float4 v = *reinterpret_cast<const float4*>(gwi + (size_t)n * 2 * H + off + k);
    ushort4 o = { f2b(v.x), f2b(v.y), f2b(v.z), f2b(v.w) };
    reinterpret_cast<ushort4*>(dst)[i] = o;
}

__global__ void embgath_kernel(const float* __restrict__ emb, const int* __restrict__ tgt,
                               unsigned short* __restrict__ dst) {
    int b = blockIdx.y, t = blockIdx.z;
    int j = blockIdx.x * 256 + threadIdx.x;
    int tok = (t == 0) ? 0 : tgt[b * T + (t - 1)];
    dst[((size_t)t * B + b) * H + j] = f2b(emb[(size_t)tok * H + j]);
}

// ---------------- big MFMA GEMM: 128x128 tile, BK=64, 512 thr (8 waves) ----------------
// C[M,N] = A[M,K](bf16) * Bw[N,K]^T + bias ; grid (M/128, N/128), x = M fast (B-tile reuse)
template <int B_F32, int OUT_BF16, int STATS>
__global__ __launch_bounds__(512) void gemm_big(const unsigned short* __restrict__ A,
                                                const void* __restrict__ Bw,
                                                const float* __restrict__ bias,
                                                void* __restrict__ Cout,
                                                float2* __restrict__ stats,
                                                int M, int N, int K) {
    __shared__ unsigned short As[128][72];
    __shared__ unsigned short Bs[128][72];
    __shared__ float mred[128][4];
    __shared__ float sred[128][4];
    const int bm = blockIdx.x * 128, bn = blockIdx.y * 128;
    const int tid = threadIdx.x, lane = tid & 63, w = tid >> 6;
    const int wm = w >> 2, wn = w & 3;
    const int quad = lane >> 4, fr = lane & 15;
    f32x4 acc[4][2] = {};

    const int srow = tid >> 2, sc16 = (tid & 3) * 16;
    for (int k0 = 0; k0 < K; k0 += 64) {
        const unsigned short* ap = A + (size_t)(bm + srow) * K + k0 + sc16;
        *reinterpret_cast<bf16x8*>(&As[srow][sc16])     = *reinterpret_cast<const bf16x8*>(ap);
        *reinterpret_cast<bf16x8*>(&As[srow][sc16 + 8]) = *reinterpret_cast<const bf16x8*>(ap + 8);
        if (B_F32) {
            const float* bp = (const float*)Bw + (size_t)(bn + srow) * K + k0 + sc16;
            float4 f0 = *reinterpret_cast<const float4*>(bp);
            float4 f1 = *reinterpret_cast<const float4*>(bp + 4);
            float4 f2 = *reinterpret_cast<const float4*>(bp + 8);
            float4 f3 = *reinterpret_cast<const float4*>(bp + 12);
            ushort8v u0, u1;
            u0[0]=f2b(f0.x); u0[1]=f2b(f0.y); u0[2]=f2b(f0.z); u0[3]=f2b(f0.w);
            u0[4]=f2b(f1.x); u0[5]=f2b(f1.y); u0[6]=f2b(f1.z); u0[7]=f2b(f1.w);
            u1[0]=f2b(f2.x); u1[1]=f2b(f2.y); u1[2]=f2b(f2.z); u1[3]=f2b(f2.w);
            u1[4]=f2b(f3.x); u1[5]=f2b(f3.y); u1[6]=f2b(f3.z); u1[7]=f2b(f3.w);
            *reinterpret_cast<ushort8v*>(&Bs[srow][sc16])     = u0;
            *reinterpret_cast<ushort8v*>(&Bs[srow][sc16 + 8]) = u1;
        } else {
            const unsigned short* bp = (const unsigned short*)Bw + (size_t)(bn + srow) * K + k0 + sc16;
            *reinterpret_cast<bf16x8*>(&Bs[srow][sc16])     = *reinterpret_cast<const bf16x8*>(bp);
            *reinterpret_cast<bf16x8*>(&Bs[srow][sc16 + 8]) = *reinterpret_cast<const bf16x8*>(bp + 8);
        }
        __syncthreads();
        #pragma unroll
        for (int ks = 0; ks < 2; ++ks) {
            const int kg = quad * 8 + 32 * ks;
            bf16x8 a[4], bb[2];
            #pragma unroll
            for (int m = 0; m < 4; ++m)
                a[m] = *reinterpret_cast<const bf16x8*>(&As[64 * wm + 16 * m + fr][kg]);
            #pragma unroll
            for (int n = 0; n < 2; ++n)
                bb[n] = *reinterpret_cast<const bf16x8*>(&Bs[32 * wn + 16 * n + fr][kg]);
            #pragma unroll
            for (int m = 0; m < 4; ++m)
                #pragma unroll
                for (int n = 0; n < 2; ++n)
                    acc[m][n] = __builtin_amdgcn_mfma_f32_16x16x32_bf16(a[m], bb[n], acc[m][n], 0, 0, 0);
        }
        __syncthreads();
    }

    // epilogue: bias + store (C/D map: col=lane&15, row=quad*4+reg)
    #pragma unroll
    for (int n = 0; n < 2; ++n) {
        int col = bn + 32 * wn + 16 * n + fr;
        float bv = bias ? bias[col] : 0.f;
        #pragma unroll
        for (int m = 0; m < 4; ++m)
            #pragma unroll
            for (int i = 0; i < 4; ++i) {
                int row = bm + 64 * wm + 16 * m + quad * 4 + i;
                float v = acc[m][n][i] + bv;
                if (OUT_BF16)
                    ((unsigned short*)Cout)[(size_t)row * N + col] = f2b(v);
                else
                    ((float*)Cout)[(size_t)row * N + col] = v;
                if (STATS) acc[m][n][i] = v;
            }
    }

    if (STATS) {
        const int nchunk = gridDim.y;
        // wave-local row max over its 32 cols
        #pragma unroll
        for (int m = 0; m < 4; ++m)
            #pragma unroll
            for (int i = 0; i < 4; ++i) {
                float x = fmaxf(acc[m][0][i], acc[m][1][i]);
                x = fmaxf(x, __shfl_xor(x, 1));
                x = fmaxf(x, __shfl_xor(x, 2));
                x = fmaxf(x, __shfl_xor(x, 4));
                x = fmaxf(x, __shfl_xor(x, 8));
                if (fr == 0) mred[64 * wm + 16 * m + quad * 4 + i][wn] = x;
            }
        __syncthreads();
        #pragma unroll
        for (int m = 0; m < 4; ++m)
            #pragma unroll
            for (int i = 0; i < 4; ++i) {
                int rl = 64 * wm + 16 * m + quad * 4 + i;
                float Mr = fmaxf(fmaxf(mred[rl][0], mred[rl][1]), fmaxf(mred[rl][2], mred[rl][3]));
                float sv = expf(acc[m][0][i] - Mr) + expf(acc[m][1][i] - Mr);
                sv += __shfl_xor(sv, 1);
                sv += __shfl_xor(sv, 2);
                sv += __shfl_xor(sv, 4);
                sv += __shfl_xor(sv, 8);
                if (fr == 0) sred[rl][wn] = sv;
            }
        __syncthreads();
        if (tid < 128) {
            float Mr = fmaxf(fmaxf(mred[tid][0], mred[tid][1]), fmaxf(mred[tid][2], mred[tid][3]));
            float Sv = sred[tid][0] + sred[tid][1] + sred[tid][2] + sred[tid][3];
            stats[(size_t)(bm + tid) * nchunk + blockIdx.y] = make_float2(Mr, Sv);
        }
    }
}

// ---------------- small MFMA GEMM: 64x64 tile, BK=64, 256 thr ----------------
// grid (N/64, M/64)
__global__ __launch_bounds__(256) void gemm_small(const unsigned short* __restrict__ A,
                                                  const unsigned short* __restrict__ Bw,
                                                  const float* __restrict__ bias,
                                                  float* __restrict__ Cout, int M, int N, int K) {
    __shared__ unsigned short As[64][72];
    __shared__ unsigned short Bs[64][72];
    const int bm = blockIdx.y * 64, bn = blockIdx.x * 64;
    const int tid = threadIdx.x, lane = tid & 63, w = tid >> 6;
    const int quad = lane >> 4, fr = lane & 15;
    f32x4 acc[4] = {}, acc2[4] = {}, acc3[4] = {}, acc4[4] = {};
    f32x4* accs[4] = { acc, acc2, acc3, acc4 };  // [m]

    const int srow = tid >> 2, sc16 = (tid & 3) * 16;
    for (int k0 = 0; k0 < K; k0 += 64) {
        const unsigned short* ap = A + (size_t)(bm + srow) * K + k0 + sc16;
        *reinterpret_cast<bf16x8*>(&As[srow][sc16])     = *reinterpret_cast<const bf16x8*>(ap);
        *reinterpret_cast<bf16x8*>(&As[srow][sc16 + 8]) = *reinterpret_cast<const bf16x8*>(ap + 8);
        const unsigned short* bp = Bw + (size_t)(bn + srow) * K + k0 + sc16;
        *reinterpret_cast<bf16x8*>(&Bs[srow][sc16])     = *reinterpret_cast<const bf16x8*>(bp);
        *reinterpret_cast<bf16x8*>(&Bs[srow][sc16 + 8]) = *reinterpret_cast<const bf16x8*>(bp + 8);
        __syncthreads();
        #pragma unroll
        for (int ks = 0; ks < 2; ++ks) {
            const int kg = quad * 8 + 32 * ks;
            bf16x8 bb = *reinterpret_cast<const bf16x8*>(&Bs[16 * w + fr][kg]);
            #pragma unroll
            for (int m = 0; m < 4; ++m) {
                bf16x8 a = *reinterpret_cast<const bf16x8*>(&As[16 * m + fr][kg]);
                accs[m][0] = __builtin_amdgcn_mfma_f32_16x16x32_bf16(a, bb, accs[m][0], 0, 0, 0);
            }
        }
        __syncthreads();
    }
    int col = bn + 16 * w + fr;
    float bv = bias ? bias[col] : 0.f;
    #pragma unroll
    for (int m = 0; m < 4; ++m)
        #pragma unroll
        for (int i = 0; i < 4; ++i) {
            int row = bm + 16 * m + quad * 4 + i;
            Cout[(size_t)row * N + col] = accs[m][0][i] + bv;
        }
}

// ---------------- fused attention: scores + softmax + ctx ----------------
// grid (B), 512 threads (8 waves). q = ghq[b, 3072:4096]
__global__ __launch_bounds__(512) void fused_attn(const float* __restrict__ ghq,
                                                  const unsigned short* __restrict__ keys,
                                                  const unsigned short* __restrict__ enc,
                                                  const float* __restrict__ va,
                                                  const float* __restrict__ va_b,
                                                  float* __restrict__ attns,
                                                  unsigned short* __restrict__ ctx_bf, int t) {
    const int b = blockIdx.x;
    const int tid = threadIdx.x, lane = tid & 63, w = tid >> 6;
    __shared__ float sh_sc[128];
    __shared__ float sh_w[128];

    // per-lane h-chunk [lane*16, lane*16+16)
    float qv[16], vv[16];
    const float* qp = ghq + (size_t)b * 4096 + H3 + lane * 16;
    const float* vp = va + lane * 16;
    #pragma unroll
    for (int j = 0; j < 16; ++j) { qv[j] = qp[j]; vv[j] = vp[j]; }

    const unsigned short* kb = keys + (size_t)b * S * H;
    for (int j = 0; j < 16; ++j) {
        int s = w * 16 + j;
        const unsigned short* kr = kb + (size_t)s * H + lane * 16;
        ushort8v k0 = *reinterpret_cast<const ushort8v*>(kr);
        ushort8v k1 = *reinterpret_cast<const ushort8v*>(kr + 8);
        float acc = 0.f;
        #pragma unroll
        for (int e = 0; e < 8; ++e) acc += tanhf(qv[e] + b2f(k0[e])) * vv[e];
        #pragma unroll
        for (int e = 0; e < 8; ++e) acc += tanhf(qv[8 + e] + b2f(k1[e])) * vv[8 + e];
        acc += __shfl_xor(acc, 1);  acc += __shfl_xor(acc, 2);
        acc += __shfl_xor(acc, 4);  acc += __shfl_xor(acc, 8);
        acc += __shfl_xor(acc, 16); acc += __shfl_xor(acc, 32);
        if (lane == 0) sh_sc[s] = acc + va_b[0];
    }
    __syncthreads();
    if (w == 0) {
        float a = sh_sc[lane], c = sh_sc[lane + 64];
        float m = fmaxf(a, c);
        m = fmaxf(m, __shfl_xor(m, 1));  m = fmaxf(m, __shfl_xor(m, 2));
        m = fmaxf(m, __shfl_xor(m, 4));  m = fmaxf(m, __shfl_xor(m, 8));
        m = fmaxf(m, __shfl_xor(m, 16)); m = fmaxf(m, __shfl_xor(m, 32));
        float e0 = expf(a - m), e1 = expf(c - m);
        float ss = e0 + e1;
        ss += __shfl_xor(ss, 1);  ss += __shfl_xor(ss, 2);
        ss += __shfl_xor(ss, 4);  ss += __shfl_xor(ss, 8);
        ss += __shfl_xor(ss, 16); ss += __shfl_xor(ss, 32);
        float w0 = e0 / ss, w1 = e1 / ss;
        sh_w[lane] = w0; sh_w[lane + 64] = w1;
        float* ap = attns + ((size_t)b * T + t) * S;
        ap[lane] = w0; ap[lane + 64] = w1;
    }
    __syncthreads();
    // ctx: 2 h per thread
    const int h2 = tid * 2;
    const unsigned short* eb = enc + (size_t)b * S * H + h2;
    float a0 = 0.f, a1 = 0.f;
    #pragma unroll 8
    for (int s = 0; s < S; ++s) {
        float wv = sh_w[s];
        unsigned int u = *reinterpret_cast<const unsigned int*>(eb + (size_t)s * H);
        a0 += wv * b2f((unsigned short)(u & 0xffff));
        a1 += wv * b2f((unsigned short)(u >> 16));
    }
    unsigned int o = ((unsigned int)f2b(a1) << 16) | f2b(a0);
    *reinterpret_cast<unsigned int*>(ctx_bf + (size_t)b * H + h2) = o;
}

// ---------------- GRU gates ----------------
__global__ void gru_kernel(const float* __restrict__ gie, const float* __restrict__ gic,
                           const float* __restrict__ ghq,
                           float* __restrict__ h, unsigned short* __restrict__ hbf,
                           unsigned short* __restrict__ outs_bf, int t) {
    const int b = blockIdx.y;
    const int j = blockIdx.x * 256 + threadIdx.x;
    const float* ge = gie + ((size_t)t * B + b) * H3;
    const float* gc = gic + (size_t)b * H3;
    const float* gh = ghq + (size_t)b * 4096;
    float r = 1.f / (1.f + expf(-(ge[j] + gc[j] + gh[j])));
    float z = 1.f / (1.f + expf(-(ge[H + j] + gc[H + j] + gh[H + j])));
    float n = tanhf(ge[2 * H + j] + gc[2 * H + j] + r * gh[2 * H + j]);
    float hv = h[(size_t)b * H + j];
    float hn = (1.f - z) * n + z * hv;
    h[(size_t)b * H + j] = hn;
    hbf[(size_t)b * H + j] = f2b(hn);
    outs_bf[((size_t)b * T + t) * H + j] = f2b(hn);
}

// ---------------- log-softmax finalize ----------------
#define NCHUNK 250
__global__ void lse_kernel(const float2* __restrict__ stats, float* __restrict__ lse) {
    const int row = blockIdx.x;
    const int tid = threadIdx.x;   // 256
    __shared__ float sh[256];
    float mv = -1e30f, sv = 0.f;
    float2 st = make_float2(-1e30f, 0.f);
    if (tid < NCHUNK) { st = stats[(size_t)row * NCHUNK + tid]; mv = st.x; }
    sh[tid] = mv; __syncthreads();
    for (int off = 128; off > 0; off >>= 1) {
        if (tid < off) sh[tid] = fmaxf(sh[tid], sh[tid + off]);
        __syncthreads();
    }
    float M = sh[0]; __syncthreads();
    if (tid < NCHUNK) sv = st.y * expf(st.x - M);
    sh[tid] = sv; __syncthreads();
    for (int off = 128; off > 0; off >>= 1) {
        if (tid < off) sh[tid] += sh[tid + off];
        __syncthreads();
    }
    if (tid == 0) lse[row] = M + logf(sh[0]);
}

__global__ void sub_lse(float* __restrict__ x, const float* __restrict__ lse) {
    const int n4 = B * T * (V / 4);
    float4* p = reinterpret_cast<float4*>(x);
    for (int i = blockIdx.x * 256 + threadIdx.x; i < n4; i += gridDim.x * 256) {
        int row = i / (V / 4);
        float l = lse[row];
        float4 v = p[i];
        v.x -= l; v.y -= l; v.z -= l; v.w -= l;
        p[i] = v;
    }
}

// ---------------- host ----------------

extern "C" void kernel_launch(void* const* d_in, const int* in_sizes, int n_in,
                              void* d_out, int out_size, void* d_ws, size_t ws_size,
                              hipStream_t stream) {
    const float* enc   = (const float*)d_in[0];
    const float* h0    = (const float*)d_in[1];
    const int*   tgt   = (const int*)d_in[2];
    const float* emb   = (const float*)d_in[3];
    const float* Wa_w  = (const float*)d_in[4];
    const float* Wa_b  = (const float*)d_in[5];
    const float* Ua_w  = (const float*)d_in[6];
    const float* Ua_b  = (const float*)d_in[7];
    const float* Va_w  = (const float*)d_in[8];
    const float* Va_b  = (const float*)d_in[9];
    const float* gwi   = (const float*)d_in[10];
    const float* gwh   = (const float*)d_in[11];
    const float* gbi   = (const float*)d_in[12];
    const float* gbh   = (const float*)d_in[13];
    const float* out_w = (const float*)d_in[14];
    const float* out_b = (const float*)d_in[15];

    float* out       = (float*)d_out;
    float* log_probs = out;                          // [B*T, V]
    float* h_final   = out + (size_t)B * T * V;      // [B, H]
    float* attns     = h_final + (size_t)B * H;      // [B, T, S]

    char* p = (char*)d_ws;
    auto alloc = [&](size_t bytes) { char* r = p; p += (bytes + 255) & ~(size_t)255; return r; };
    unsigned short* ua_bf   = (unsigned short*)alloc((size_t)B * S * H * 2);
    unsigned short* enc_bf  = (unsigned short*)alloc((size_t)B * S * H * 2);
    unsigned short* Ua_bf   = (unsigned short*)alloc((size_t)H * H * 2);
    unsigned short* Wcat    = (unsigned short*)alloc((size_t)4096 * H * 2);
    unsigned short* Wctx    = (unsigned short*)alloc((size_t)H3 * H * 2);
    unsigned short* Wemb    = (unsigned short*)alloc((size_t)H3 * H * 2);
    float*          catbias = (float*)alloc(4096 * 4);
    unsigned short* embg    = (unsigned short*)alloc((size_t)T * B * H * 2);
    float*          gi_emb  = (float*)alloc((size_t)T * B * H3 * 4);
    float*          hbuf    = (float*)alloc((size_t)B * H * 4);
    unsigned short* hbf     = (unsigned short*)alloc((size_t)B * H * 2);
    float*          ghq     = (float*)alloc((size_t)B * 4096 * 4);
    unsigned short* ctx_bf  = (unsigned short*)alloc((size_t)B * H * 2);
    float*          gi_ctx  = (float*)alloc((size_t)B * H3 * 4);
    unsigned short* outs_bf = (unsigned short*)alloc((size_t)B * T * H * 2);
    float2*         stats   = (float2*)alloc((size_t)B * T * NCHUNK * 8);
    float*          lse     = (float*)alloc((size_t)B * T * 4);

    // one-time builds
    conv_f2b<<<B * S * H / 4 / 256, 256, 0, stream>>>(enc, enc_bf, B * S * H / 4);
    conv_f2b<<<H * H / 4 / 256, 256, 0, stream>>>(Ua_w, Ua_bf, H * H / 4);
    conv_f2b<<<B * H / 4 / 256, 256, 0, stream>>>(h0, hbf, B * H / 4);
    build_wcat<<<4096 * H / 4 / 256, 256, 0, stream>>>(gwh, Wa_w, Wcat);
    build_catbias<<<4096 / 256, 256, 0, stream>>>(gbh, Wa_b, catbias);
    build_wslice<<<H3 * H / 4 / 256, 256, 0, stream>>>(gwi, Wemb, 0);
    build_wslice<<<H3 * H / 4 / 256, 256, 0, stream>>>(gwi, Wctx, H);
    embgath_kernel<<<dim3(H / 256, B, T), 256, 0, stream>>>(emb, tgt, embg);
    hipMemcpyAsync(hbuf, h0, (size_t)B * H * sizeof(float), hipMemcpyDeviceToDevice, stream);

    // ua_keys = enc @ Ua_w^T + Ua_b  -> bf16 [B*S, H]
    gemm_big<0, 1, 0><<<dim3(B * S / 128, H / 128), 512, 0, stream>>>(
        enc_bf, Ua_bf, Ua_b, ua_bf, nullptr, B * S, H, H);
    // gi_emb = embg @ Wemb^T + gbi  [T*B, 3072]
    gemm_big<0, 0, 0><<<dim3(T * B / 128, H3 / 128), 512, 0, stream>>>(
        embg, Wemb, gbi, gi_emb, nullptr, T * B, H3, H);

    for (int t = 0; t < T; ++t) {
        // [gh | q] = h @ [gwh; Wa_w]^T + [gbh; Wa_b]  [64, 4096]
        gemm_small<<<dim3(4096 / 64, 1), 256, 0, stream>>>(hbf, Wcat, catbias, ghq, B, 4096, H);
        fused_attn<<<B, 512, 0, stream>>>(ghq, ua_bf, enc_bf, Va_w, Va_b, attns, ctx_bf, t);
        // gi_ctx = ctx @ gru_wi[:, H:2H]^T  [64, 3072]
        gemm_small<<<dim3(H3 / 64, 1), 256, 0, stream>>>(ctx_bf, Wctx, nullptr, gi_ctx, B, H3, H);
        gru_kernel<<<dim3(H / 256, B), 256, 0, stream>>>(gi_emb, gi_ctx, ghq, hbuf, hbf, outs_bf, t);
    }

    // logits + fused softmax stats; out_w read fp32 directly
    gemm_big<1, 0, 1><<<dim3(B * T / 128, V / 128), 512, 0, stream>>>(
        outs_bf, out_w, out_b, log_probs, stats, B * T, V, H);
    lse_kernel<<<B * T, 256, 0, stream>>>(stats, lse);
    sub_lse<<<2048, 256, 0, stream>>>(log_probs, lse);

    hipMemcpyAsync(h_final, hbuf, (size_t)B * H * sizeof(float), hipMemcpyDeviceToDevice, stream);
}